// Round 4
// baseline (336.470 us; speedup 1.0000x reference)
//
#include <hip/hip_runtime.h>
#include <math.h>

// RouterLite v8 = v7 with kA_attn K-split doubled 8 -> 16.
// v7 kA counters: dur 67.8us, MfmaUtil 4.5%, VALUBusy 8.5%, HBM 4.8%,
// Occupancy 20.7% (grid 512 blocks = 2 waves/SIMD) -> pure latency exposure
// (8.6 GFLOP needs ~4us of MFMA pipe). v8: split 16 -> 1024 blocks = 4
// waves/SIMD; per-wave its 8->4. OP doubles to the full dead-Xbf region
// (exact fit 8388608 fl); LW moves into dead HP region; kC sums 16 splits.
//
// ws map (float offsets), total ~61.9 MB:
//   Xbf  @0         [8192][2048] bf16 (8388608 fl) — dead after k2_mfma,
//                   ALIASED by OP @0 [16][4096][128] fp32 (exact fit)
//   HP   @8388608   [2][8192][256] fp32 partials (k2->k3, dead after),
//                   ALIASED by LW @8388608 [16][4096][2] fp32 (kA->kC)
//   Wbf  @12582912  [512][2048] bf16 (W1q rows 0..255, W1r 256..511)
//   Z    @13107200  [8192][128] fp32
//   Zbf  @14155776  [8192][128] bf16
//   ZbfT @14680064  [128][4096] bf16 (Z_r transposed)
//   RB   @14942208  [4096][128]
//   COS  @15466496  [4096]
//   ILW  @15470592  [4096][2]
// d_out: fp32, [0..4095]=raw_logit, [4096..8191]=delta_theta.

#define HD   2048
#define D2   256
#define DD   128
#define NQ   4096
#define NT   8192
#define NSPLIT 16
#define KPS  (NQ / NSPLIT)   // 256 K-rows per split
#define NIT  (KPS / 64)      // 4 iterations of 64 K-rows

typedef __attribute__((ext_vector_type(8))) short s16x8;
typedef __attribute__((ext_vector_type(4))) float f32x4;

static __device__ __forceinline__ float gelu_exact(float x){
    return 0.5f * x * (1.0f + erff(x * 0.7071067811865475f));
}
static __device__ __forceinline__ unsigned short f2bf(float f){
    unsigned int u = __float_as_uint(f);
    return (unsigned short)((u + 0x7FFFu + ((u >> 16) & 1u)) >> 16);
}
static __device__ __forceinline__ unsigned int pack2bf(float a, float b){
    return (unsigned int)f2bf(a) | ((unsigned int)f2bf(b) << 16);
}

// ---------------- KLN: LN(x) -> bf16 Xbf (blocks 0..8191); W1 -> bf16 Wbf (8192..8703)
__global__ __launch_bounds__(256)
void kLN_cast(const float* __restrict__ q, const float* __restrict__ R,
              const float* __restrict__ gq, const float* __restrict__ bq,
              const float* __restrict__ gr, const float* __restrict__ br,
              const float* __restrict__ W1q, const float* __restrict__ W1r,
              unsigned short* __restrict__ Xbf, unsigned short* __restrict__ Wbf){
    const int r = blockIdx.x;
    const int tid = threadIdx.x;
    if (r >= NT){
        const int rw = r - NT;
        const float* src = (rw >= 256) ? (W1r + (size_t)(rw - 256) * HD)
                                       : (W1q + (size_t)rw * HD);
        float4 a = *(const float4*)&src[tid * 8];
        float4 c = *(const float4*)&src[tid * 8 + 4];
        uint4 p = {pack2bf(a.x, a.y), pack2bf(a.z, a.w),
                   pack2bf(c.x, c.y), pack2bf(c.z, c.w)};
        *(uint4*)&Wbf[(size_t)rw * HD + tid * 8] = p;
        return;
    }
    const float* src = (r < NQ) ? (q + (size_t)r * HD) : (R + (size_t)(r - NQ) * HD);
    const float* g  = (r < NQ) ? gq : gr;
    const float* bb = (r < NQ) ? bq : br;
    float4 x0 = *(const float4*)&src[tid * 8];
    float4 x1 = *(const float4*)&src[tid * 8 + 4];
    float v[8] = {x0.x, x0.y, x0.z, x0.w, x1.x, x1.y, x1.z, x1.w};
    float s = 0.f, sq = 0.f;
#pragma unroll
    for (int i = 0; i < 8; ++i){ s += v[i]; sq += v[i] * v[i]; }
    __shared__ float red[256];
    __shared__ float mS, rS;
    red[tid] = s; __syncthreads();
    for (int off = 128; off > 0; off >>= 1){
        if (tid < off) red[tid] += red[tid + off];
        __syncthreads();
    }
    float sum = red[0]; __syncthreads();
    red[tid] = sq; __syncthreads();
    for (int off = 128; off > 0; off >>= 1){
        if (tid < off) red[tid] += red[tid + off];
        __syncthreads();
    }
    if (tid == 0){
        float mean = sum * (1.0f / HD);
        float var  = red[0] * (1.0f / HD) - mean * mean;
        mS = mean;
        rS = rsqrtf(fmaxf(var, 0.0f) + 1e-5f);
    }
    __syncthreads();
    float mean = mS, rstd = rS;
    float4 g0 = *(const float4*)&g[tid * 8];
    float4 g1 = *(const float4*)&g[tid * 8 + 4];
    float4 b0 = *(const float4*)&bb[tid * 8];
    float4 b1 = *(const float4*)&bb[tid * 8 + 4];
    float gg[8] = {g0.x, g0.y, g0.z, g0.w, g1.x, g1.y, g1.z, g1.w};
    float bv[8] = {b0.x, b0.y, b0.z, b0.w, b1.x, b1.y, b1.z, b1.w};
    float h[8];
#pragma unroll
    for (int i = 0; i < 8; ++i) h[i] = (v[i] - mean) * rstd * gg[i] + bv[i];
    uint4 p = {pack2bf(h[0], h[1]), pack2bf(h[2], h[3]),
               pack2bf(h[4], h[5]), pack2bf(h[6], h[7])};
    *(uint4*)&Xbf[(size_t)r * HD + tid * 8] = p;
}

// ---------------- K2: HP[ks] = Xbf @ Wbf^T (K-half ks), bf16 MFMA.
// grid (128 m-blocks of 64, 2 n-blocks of 128, 2 K-splits), 256 thr = 4 waves.
// Wave: 32m x 64n = 2x4 tiles of 16x16. Direct global s16x8 fragment loads.
__global__ __launch_bounds__(256)
void k2_mfma(const unsigned short* __restrict__ Xbf,
             const unsigned short* __restrict__ Wbf,
             float* __restrict__ HP){
    const int tid  = threadIdx.x;
    const int wave = tid >> 6, lane = tid & 63;
    const int quad = lane >> 4, col = lane & 15;
    const int mblk = blockIdx.x;
    const int nblk = blockIdx.y;
    const int ks   = blockIdx.z;
    const int inp  = mblk >> 6;
    const int mbase = mblk * 64 + (wave & 1) * 32;
    const int nbase = nblk * 128 + (wave >> 1) * 64;

    const unsigned short* A0 = Xbf + (size_t)(mbase + col) * HD + ks * 1024 + quad * 8;
    const unsigned short* A1 = A0 + (size_t)16 * HD;
    const unsigned short* B0 = Wbf + (size_t)(inp * 256 + nbase + col) * HD + ks * 1024 + quad * 8;
    const unsigned short* B1 = B0 + (size_t)16 * HD;
    const unsigned short* B2 = B0 + (size_t)32 * HD;
    const unsigned short* B3 = B0 + (size_t)48 * HD;

    f32x4 acc[2][4];
#pragma unroll
    for (int mi = 0; mi < 2; ++mi)
#pragma unroll
        for (int ni = 0; ni < 4; ++ni) acc[mi][ni] = (f32x4){0.f, 0.f, 0.f, 0.f};

    for (int s = 0; s < 32; ++s){
        const int ko = s * 32;
        s16x8 a0 = *(const s16x8*)(A0 + ko);
        s16x8 a1 = *(const s16x8*)(A1 + ko);
        s16x8 b0 = *(const s16x8*)(B0 + ko);
        s16x8 b1 = *(const s16x8*)(B1 + ko);
        s16x8 b2 = *(const s16x8*)(B2 + ko);
        s16x8 b3 = *(const s16x8*)(B3 + ko);
        acc[0][0] = __builtin_amdgcn_mfma_f32_16x16x32_bf16(a0, b0, acc[0][0], 0, 0, 0);
        acc[0][1] = __builtin_amdgcn_mfma_f32_16x16x32_bf16(a0, b1, acc[0][1], 0, 0, 0);
        acc[0][2] = __builtin_amdgcn_mfma_f32_16x16x32_bf16(a0, b2, acc[0][2], 0, 0, 0);
        acc[0][3] = __builtin_amdgcn_mfma_f32_16x16x32_bf16(a0, b3, acc[0][3], 0, 0, 0);
        acc[1][0] = __builtin_amdgcn_mfma_f32_16x16x32_bf16(a1, b0, acc[1][0], 0, 0, 0);
        acc[1][1] = __builtin_amdgcn_mfma_f32_16x16x32_bf16(a1, b1, acc[1][1], 0, 0, 0);
        acc[1][2] = __builtin_amdgcn_mfma_f32_16x16x32_bf16(a1, b2, acc[1][2], 0, 0, 0);
        acc[1][3] = __builtin_amdgcn_mfma_f32_16x16x32_bf16(a1, b3, acc[1][3], 0, 0, 0);
    }
    float* dst = HP + (size_t)ks * NT * D2;
#pragma unroll
    for (int mi = 0; mi < 2; ++mi){
#pragma unroll
        for (int ni = 0; ni < 4; ++ni){
#pragma unroll
            for (int reg = 0; reg < 4; ++reg){
                int m = mbase + mi * 16 + quad * 4 + reg;
                int n = nbase + ni * 16 + col;
                dst[(size_t)m * D2 + n] = acc[mi][ni][reg];
            }
        }
    }
}

// ---------------- K3: combine HP + bias + GELU, GEMM2, l2norm -> Z (fp32), Zbf (bf16)
__global__ __launch_bounds__(256)
void k3_gemm2(const float* __restrict__ HP,
              const float* __restrict__ b1q, const float* __restrict__ b1r,
              const float* __restrict__ W2q, const float* __restrict__ b2q,
              const float* __restrict__ W2r, const float* __restrict__ b2r,
              float* __restrict__ Z, unsigned short* __restrict__ Zbf){
    const int gstart = blockIdx.x * 32;
    const int inp = (gstart >= NQ) ? 1 : 0;
    const float* b1 = inp ? b1r : b1q;
    const float* W2 = inp ? W2r : W2q;
    const float* b2 = inp ? b2r : b2q;

    __shared__ __align__(16) float Hs[32][68];
    __shared__ __align__(16) float Wk[64][132];
    __shared__ float red[32][17];
    __shared__ float normS[32];

    const int tid = threadIdx.x;
    const int ty = tid >> 4;
    const int tx = tid & 15;

    float acc[2][8];
#pragma unroll
    for (int jj = 0; jj < 8; ++jj){ acc[0][jj] = 0.f; acc[1][jj] = 0.f; }

    for (int kc = 0; kc < 4; ++kc){
#pragma unroll
        for (int i = 0; i < 8; ++i){
            int e = tid + i * 256;
            int rr = e >> 6, kk = e & 63;
            size_t idx = (size_t)(gstart + rr) * D2 + kc * 64 + kk;
            float hv = HP[idx] + HP[(size_t)NT * D2 + idx] + b1[kc * 64 + kk];
            Hs[rr][kk] = gelu_exact(hv);
        }
#pragma unroll
        for (int i = 0; i < 32; ++i){
            int e = tid + i * 256;
            int nn = e >> 6, kk = e & 63;
            Wk[kk][nn] = W2[(size_t)nn * D2 + kc * 64 + kk];
        }
        __syncthreads();
#pragma unroll
        for (int k4 = 0; k4 < 16; ++k4){
            float a0[4], a1[4];
            float4 t0 = *(const float4*)&Hs[ty * 2][k4 * 4];
            a0[0] = t0.x; a0[1] = t0.y; a0[2] = t0.z; a0[3] = t0.w;
            float4 t1 = *(const float4*)&Hs[ty * 2 + 1][k4 * 4];
            a1[0] = t1.x; a1[1] = t1.y; a1[2] = t1.z; a1[3] = t1.w;
#pragma unroll
            for (int kq = 0; kq < 4; ++kq){
                float4 w0 = *(const float4*)&Wk[k4 * 4 + kq][tx * 8];
                float4 w1 = *(const float4*)&Wk[k4 * 4 + kq][tx * 8 + 4];
                float wv[8] = {w0.x, w0.y, w0.z, w0.w, w1.x, w1.y, w1.z, w1.w};
#pragma unroll
                for (int jj = 0; jj < 8; ++jj){
                    acc[0][jj] += a0[kq] * wv[jj];
                    acc[1][jj] += a1[kq] * wv[jj];
                }
            }
        }
        __syncthreads();
    }
    float v0[8], v1[8];
    float sq0 = 0.f, sq1 = 0.f;
#pragma unroll
    for (int jj = 0; jj < 8; ++jj){
        int c = tx * 8 + jj;
        v0[jj] = acc[0][jj] + b2[c];
        v1[jj] = acc[1][jj] + b2[c];
        sq0 += v0[jj] * v0[jj];
        sq1 += v1[jj] * v1[jj];
    }
    red[ty * 2][tx]     = sq0;
    red[ty * 2 + 1][tx] = sq1;
    __syncthreads();
    if (tid < 32){
        float s = 0.f;
#pragma unroll
        for (int t = 0; t < 16; ++t) s += red[tid][t];
        normS[tid] = 1.0f / fmaxf(sqrtf(s), 1e-12f);
    }
    __syncthreads();
    float s0 = normS[ty * 2], s1 = normS[ty * 2 + 1];
    int row0 = gstart + ty * 2, row1 = row0 + 1;
    size_t o0 = (size_t)row0 * DD + tx * 8;
    size_t o1 = (size_t)row1 * DD + tx * 8;
    float z0[8], z1[8];
#pragma unroll
    for (int jj = 0; jj < 8; ++jj){ z0[jj] = v0[jj] * s0; z1[jj] = v1[jj] * s1; }
    float4 a = {z0[0], z0[1], z0[2], z0[3]}, b = {z0[4], z0[5], z0[6], z0[7]};
    float4 c = {z1[0], z1[1], z1[2], z1[3]}, d = {z1[4], z1[5], z1[6], z1[7]};
    *(float4*)&Z[o0]     = a;  *(float4*)&Z[o0 + 4] = b;
    *(float4*)&Z[o1]     = c;  *(float4*)&Z[o1 + 4] = d;
    uint4 p0 = {pack2bf(z0[0], z0[1]), pack2bf(z0[2], z0[3]),
                pack2bf(z0[4], z0[5]), pack2bf(z0[6], z0[7])};
    uint4 p1 = {pack2bf(z1[0], z1[1]), pack2bf(z1[2], z1[3]),
                pack2bf(z1[4], z1[5]), pack2bf(z1[6], z1[7])};
    *(uint4*)&Zbf[o0] = p0;
    *(uint4*)&Zbf[o1] = p1;
}

// ---------------- KT: ZbfT[d][r] = Zbf[NQ + r][d]  (r part only), tile 64x128.
__global__ __launch_bounds__(256)
void kT_transpose(const unsigned short* __restrict__ Zbf,
                  unsigned short* __restrict__ ZbfT){
    __shared__ unsigned short Ts[64][129];
    const int r0 = blockIdx.x * 64;
    const int tid = threadIdx.x;
#pragma unroll
    for (int i = 0; i < 32; ++i){
        int e = tid + i * 256;
        int rr = e >> 7, dd = e & 127;
        Ts[rr][dd] = Zbf[(size_t)(NQ + r0 + rr) * DD + dd];
    }
    __syncthreads();
#pragma unroll
    for (int i = 0; i < 32; ++i){
        int e = tid + i * 256;
        int dd = e >> 6, rr = e & 63;
        ZbfT[(size_t)dd * NQ + r0 + rr] = Ts[rr][dd];
    }
}

// ---------------- KA: flash attention pass (bf16 MFMA), K-split = NSPLIT.
__global__ __launch_bounds__(256)
void kA_attn(const unsigned short* __restrict__ Zbf,
             const unsigned short* __restrict__ ZbfT,
             float* __restrict__ OP, float* __restrict__ LW){
    const int tid  = threadIdx.x;
    const int wave = tid >> 6, lane = tid & 63;
    const int quad = lane >> 4, col = lane & 15;
    const int m0   = blockIdx.x * 64 + wave * 16;
    const int split = blockIdx.y;
    const float scl = 0.08838834764831845f;   // 1/sqrt(128)

    __shared__ __align__(16) unsigned short Pt[4][16][72];  // per-wave [m][r]

    s16x8 aq[4];
#pragma unroll
    for (int kb = 0; kb < 4; ++kb)
        aq[kb] = *(const s16x8*)&Zbf[(size_t)(m0 + col) * DD + kb * 32 + quad * 8];

    f32x4 o[8];
#pragma unroll
    for (int dt = 0; dt < 8; ++dt) o[dt] = (f32x4){0.f, 0.f, 0.f, 0.f};
    float lp[4] = {0.f, 0.f, 0.f, 0.f}, wp[4] = {0.f, 0.f, 0.f, 0.f};

    for (int it = 0; it < NIT; ++it){
        const int r0 = split * KPS + it * 64;
#pragma unroll
        for (int nt = 0; nt < 4; ++nt){
            f32x4 s = (f32x4){0.f, 0.f, 0.f, 0.f};
#pragma unroll
            for (int kb = 0; kb < 4; ++kb){
                s16x8 b = *(const s16x8*)&Zbf[(size_t)(NQ + r0 + nt * 16 + col) * DD + kb * 32 + quad * 8];
                s = __builtin_amdgcn_mfma_f32_16x16x32_bf16(aq[kb], b, s, 0, 0, 0);
            }
#pragma unroll
            for (int reg = 0; reg < 4; ++reg){
                float sv = s[reg] * scl;
                float e  = __expf(sv);
                lp[reg] += e;
                wp[reg] += e * sv;
                Pt[wave][quad * 4 + reg][nt * 16 + col] = f2bf(e);
            }
        }
        s16x8 ap[2];
#pragma unroll
        for (int kb2 = 0; kb2 < 2; ++kb2)
            ap[kb2] = *(const s16x8*)&Pt[wave][col][kb2 * 32 + quad * 8];
#pragma unroll
        for (int dt = 0; dt < 8; ++dt){
#pragma unroll
            for (int kb2 = 0; kb2 < 2; ++kb2){
                s16x8 b = *(const s16x8*)&ZbfT[(size_t)(dt * 16 + col) * NQ + r0 + kb2 * 32 + quad * 8];
                o[dt] = __builtin_amdgcn_mfma_f32_16x16x32_bf16(ap[kb2], b, o[dt], 0, 0, 0);
            }
        }
    }
#pragma unroll
    for (int reg = 0; reg < 4; ++reg){
        float l = lp[reg], w = wp[reg];
        l += __shfl_xor(l, 8);  w += __shfl_xor(w, 8);
        l += __shfl_xor(l, 4);  w += __shfl_xor(w, 4);
        l += __shfl_xor(l, 2);  w += __shfl_xor(w, 2);
        l += __shfl_xor(l, 1);  w += __shfl_xor(w, 1);
        if (col == 0){
            int row = m0 + quad * 4 + reg;
            LW[((size_t)split * NQ + row) * 2]     = l;
            LW[((size_t)split * NQ + row) * 2 + 1] = w;
        }
    }
#pragma unroll
    for (int dt = 0; dt < 8; ++dt){
#pragma unroll
        for (int reg = 0; reg < 4; ++reg){
            int row = m0 + quad * 4 + reg;
            OP[((size_t)split * NQ + row) * DD + dt * 16 + col] = o[dt][reg];
        }
    }
}

// ---------------- KC: combine NSPLIT splits -> r_bar, cos, u_n.
__global__ __launch_bounds__(128)
void kC_combine(const float* __restrict__ OP, const float* __restrict__ LW,
                const float* __restrict__ Z,
                float* __restrict__ RB, float* __restrict__ COS,
                float* __restrict__ ILW){
    const int r = blockIdx.x;
    const int c = threadIdx.x;
    float v = 0.f;
#pragma unroll
    for (int s = 0; s < NSPLIT; ++s) v += OP[((size_t)s * NQ + r) * DD + c];
    __shared__ float red[128];
    red[c] = v * v; __syncthreads();
    for (int off = 64; off > 0; off >>= 1){
        if (c < off) red[c] += red[c + off];
        __syncthreads();
    }
    float scale = 1.0f / fmaxf(sqrtf(red[0]), 1e-12f);
    __syncthreads();
    float rb = v * scale;
    RB[(size_t)r * DD + c] = rb;
    float zq = Z[(size_t)r * DD + c];
    red[c] = zq * rb; __syncthreads();
    for (int off = 64; off > 0; off >>= 1){
        if (c < off) red[c] += red[c + off];
        __syncthreads();
    }
    if (c == 0){
        COS[r] = red[0];
        float l = 0.f, w = 0.f;
#pragma unroll
        for (int s = 0; s < NSPLIT; ++s){
            l += LW[((size_t)s * NQ + r) * 2];
            w += LW[((size_t)s * NQ + r) * 2 + 1];
        }
        float ent = logf(l) - w / l;
        ILW[2 * r]     = 1.0f / l;
        ILW[2 * r + 1] = ent * (1.0f / 8.317766166719343f);  // / ln(4096)
    }
}

// ---------------- K8 v7: decoder MLP, occupancy-oriented rewrite.
// 1024 blocks x 256 thr (4 waves), 4 rows/block. LDS = 4KB Xs + 32B partials.
__global__ __launch_bounds__(256)
void k8_decoder(const float* __restrict__ Z, const float* __restrict__ RB,
                const float* __restrict__ ILW, const float* __restrict__ COS,
                const float* __restrict__ gd, const float* __restrict__ bd,
                const float* __restrict__ W1d, const float* __restrict__ b1d,
                const float* __restrict__ W2d, const float* __restrict__ b2d,
                const float* __restrict__ beta, const float* __restrict__ W_len,
                const float* __restrict__ b_len,
                float* __restrict__ out){
    const int r0 = blockIdx.x * 4;
    const int tid = threadIdx.x;
    const int wave = tid >> 6, lane = tid & 63;

    __shared__ __align__(16) float Xs[4][256];
    __shared__ float pr[4][2];

    // ---- LN for row (r0+wave), one wave per row, shfl-only reduction.
    {
        const int row = r0 + wave;
        const int c0 = lane * 4;
        float4 v;
        if (c0 < DD) v = *(const float4*)&Z[(size_t)row * DD + c0];
        else         v = *(const float4*)&RB[(size_t)row * DD + (c0 - DD)];
        float s  = v.x + v.y + v.z + v.w;
        float sq = v.x * v.x + v.y * v.y + v.z * v.z + v.w * v.w;
#pragma unroll
        for (int off = 32; off > 0; off >>= 1){
            s  += __shfl_xor(s, off);
            sq += __shfl_xor(sq, off);
        }
        float mean = s * (1.0f / D2);
        float var  = sq * (1.0f / D2) - mean * mean;
        float rstd = rsqrtf(fmaxf(var, 0.0f) + 1e-5f);
        float4 g = *(const float4*)&gd[c0];
        float4 b = *(const float4*)&bd[c0];
        float4 xn;
        xn.x = (v.x - mean) * rstd * g.x + b.x;
        xn.y = (v.y - mean) * rstd * g.y + b.y;
        xn.z = (v.z - mean) * rstd * g.z + b.z;
        xn.w = (v.w - mean) * rstd * g.w + b.w;
        *(float4*)&Xs[wave][c0] = xn;
    }
    __syncthreads();

    // ---- GEMM1 + GELU + W2 dot. Thread: hidden unit j, row pair rp.
    const int j  = tid & 127;
    const int rp = tid >> 7;     // waves 0,1 -> rows 0,1 ; waves 2,3 -> rows 2,3
    const float* wrow = W1d + (size_t)j * D2;
    const float* xa = &Xs[rp * 2][0];
    const float* xb = &Xs[rp * 2 + 1][0];
    float h0 = 0.f, h1 = 0.f;
#pragma unroll 8
    for (int k = 0; k < D2; k += 4){
        float4 w  = *(const float4*)&wrow[k];
        float4 a4 = *(const float4*)&xa[k];
        float4 b4 = *(const float4*)&xb[k];
        h0 += w.x * a4.x + w.y * a4.y + w.z * a4.z + w.w * a4.w;
        h1 += w.x * b4.x + w.y * b4.y + w.z * b4.z + w.w * b4.w;
    }
    float bj = b1d[j];
    h0 = gelu_exact(h0 + bj);
    h1 = gelu_exact(h1 + bj);
    float w2 = W2d[j];
    float p0 = h0 * w2, p1 = h1 * w2;
#pragma unroll
    for (int off = 32; off > 0; off >>= 1){
        p0 += __shfl_xor(p0, off);
        p1 += __shfl_xor(p1, off);
    }
    if (lane == 0){ pr[wave][0] = p0; pr[wave][1] = p1; }
    __syncthreads();

    // ---- Final logit + scalar heads: threads 0..3, one row each.
    if (tid < 4){
        const int row   = tid;
        const int rpair = row >> 1, rlo = row & 1;
        float lg = b2d[0] + pr[rpair * 2][rlo] + pr[rpair * 2 + 1][rlo];
        const int gr = r0 + row;
        float u  = ILW[2 * gr + 1];
        float cv = COS[gr];
        float dln = cv * W_len[0] + u * W_len[1] + b_len[0];
        float dt = beta[0] * u + beta[1] * tanhf(dln);
        dt = fminf(0.5f, fmaxf(-0.5f, dt));
        out[gr]      = lg;
        out[NQ + gr] = dt;
    }
}

extern "C" void kernel_launch(void* const* d_in, const int* in_sizes, int n_in,
                              void* d_out, int out_size, void* d_ws, size_t ws_size,
                              hipStream_t stream){
    const float* q      = (const float*)d_in[0];
    const float* R      = (const float*)d_in[1];
    const float* ln_q_g = (const float*)d_in[2];
    const float* ln_q_b = (const float*)d_in[3];
    const float* W1q    = (const float*)d_in[4];
    const float* b1q    = (const float*)d_in[5];
    const float* W2q    = (const float*)d_in[6];
    const float* b2q    = (const float*)d_in[7];
    const float* ln_r_g = (const float*)d_in[8];
    const float* ln_r_b = (const float*)d_in[9];
    const float* W1r    = (const float*)d_in[10];
    const float* b1r    = (const float*)d_in[11];
    const float* W2r    = (const float*)d_in[12];
    const float* b2r    = (const float*)d_in[13];
    const float* ln_d_g = (const float*)d_in[14];
    const float* ln_d_b = (const float*)d_in[15];
    const float* W1d    = (const float*)d_in[16];
    const float* b1d    = (const float*)d_in[17];
    const float* W2d    = (const float*)d_in[18];
    const float* b2d    = (const float*)d_in[19];
    const float* beta   = (const float*)d_in[20];
    const float* W_len  = (const float*)d_in[21];
    const float* b_len  = (const float*)d_in[22];

    float* WS = (float*)d_ws;
    unsigned short* Xbf  = (unsigned short*)(WS);             // 8192*2048 bf16 = 8388608 fl
    float* OP    = WS;                                        // [16][4096][128] aliases Xbf (dead after k2) — exact fit
    float* HP    = WS + 8388608;                              // 2*8192*256
    float* LW    = WS + 8388608;                              // [16][4096][2] aliases HP (dead after k3)
    unsigned short* Wbf  = (unsigned short*)(WS + 12582912);  // 512*2048 bf16
    float* Z     = WS + 13107200;                             // 8192*128
    unsigned short* Zbf  = (unsigned short*)(WS + 14155776);  // 8192*128 bf16
    unsigned short* ZbfT = (unsigned short*)(WS + 14680064);  // 128*4096 bf16
    float* RB    = WS + 14942208;                             // 4096*128
    float* COSV  = WS + 15466496;                             // 4096
    float* ILW   = WS + 15470592;                             // 4096*2
    float* out   = (float*)d_out;

    hipLaunchKernelGGL(kLN_cast, dim3(NT + 512), dim3(256), 0, stream,
                       q, R, ln_q_g, ln_q_b, ln_r_g, ln_r_b, W1q, W1r, Xbf, Wbf);
    hipLaunchKernelGGL(k2_mfma, dim3(128, 2, 2), dim3(256), 0, stream, Xbf, Wbf, HP);
    hipLaunchKernelGGL(k3_gemm2, dim3(256), dim3(256), 0, stream,
                       HP, b1q, b1r, W2q, b2q, W2r, b2r, Z, Zbf);
    hipLaunchKernelGGL(kT_transpose, dim3(64), dim3(256), 0, stream, Zbf, ZbfT);
    hipLaunchKernelGGL(kA_attn, dim3(64, NSPLIT), dim3(256), 0, stream, Zbf, ZbfT, OP, LW);
    hipLaunchKernelGGL(kC_combine, dim3(NQ), dim3(128), 0, stream, OP, LW, Z, RB, COSV, ILW);
    hipLaunchKernelGGL(k8_decoder, dim3(1024), dim3(256), 0, stream,
                       Z, RB, ILW, COSV, ln_d_g, ln_d_b, W1d, b1d, W2d, b2d,
                       beta, W_len, b_len, out);
}

// Round 5
// 305.341 us; speedup vs baseline: 1.1019x; 1.1019x over previous
//
#include <hip/hip_runtime.h>
#include <math.h>

// RouterLite v9 = v8 with kA_attn restructured for ILP (v8 post-mortem:
// more waves did NOT help -> per-wave serial chain is the limiter. VGPR=84
// showed zero prefetch headroom; 16-row m-tile = 1 MFMA per 16B load).
// v9 kA: 32-row m-tile per wave (block 4 waves x 32 = 128 q-rows, grid
// 32 x NSPLIT=16 = 512 blocks), explicit V-prefetch regs (bv[8][2]) issued
// before QK+exp so V latency hides; same loads now feed 2x the MFMAs;
// L2 traffic halves. launch_bounds(256,2) -> up to 256 VGPR, 2 waves/SIMD.
//
// ws map (float offsets), total ~61.9 MB:
//   Xbf  @0         [8192][2048] bf16 (8388608 fl) — dead after k2_mfma,
//                   ALIASED by OP @0 [16][4096][128] fp32 (exact fit)
//   HP   @8388608   [2][8192][256] fp32 partials (k2->k3, dead after),
//                   ALIASED by LW @8388608 [16][4096][2] fp32 (kA->kC)
//   Wbf  @12582912  [512][2048] bf16 (W1q rows 0..255, W1r 256..511)
//   Z    @13107200  [8192][128] fp32
//   Zbf  @14155776  [8192][128] bf16
//   ZbfT @14680064  [128][4096] bf16 (Z_r transposed)
//   RB   @14942208  [4096][128]
//   COS  @15466496  [4096]
//   ILW  @15470592  [4096][2]
// d_out: fp32, [0..4095]=raw_logit, [4096..8191]=delta_theta.

#define HD   2048
#define D2   256
#define DD   128
#define NQ   4096
#define NT   8192
#define NSPLIT 16
#define KPS  (NQ / NSPLIT)   // 256 K-rows per split
#define NIT  (KPS / 64)      // 4 iterations of 64 K-rows

typedef __attribute__((ext_vector_type(8))) short s16x8;
typedef __attribute__((ext_vector_type(4))) float f32x4;

static __device__ __forceinline__ float gelu_exact(float x){
    return 0.5f * x * (1.0f + erff(x * 0.7071067811865475f));
}
static __device__ __forceinline__ unsigned short f2bf(float f){
    unsigned int u = __float_as_uint(f);
    return (unsigned short)((u + 0x7FFFu + ((u >> 16) & 1u)) >> 16);
}
static __device__ __forceinline__ unsigned int pack2bf(float a, float b){
    return (unsigned int)f2bf(a) | ((unsigned int)f2bf(b) << 16);
}

// ---------------- KLN: LN(x) -> bf16 Xbf (blocks 0..8191); W1 -> bf16 Wbf (8192..8703)
__global__ __launch_bounds__(256)
void kLN_cast(const float* __restrict__ q, const float* __restrict__ R,
              const float* __restrict__ gq, const float* __restrict__ bq,
              const float* __restrict__ gr, const float* __restrict__ br,
              const float* __restrict__ W1q, const float* __restrict__ W1r,
              unsigned short* __restrict__ Xbf, unsigned short* __restrict__ Wbf){
    const int r = blockIdx.x;
    const int tid = threadIdx.x;
    if (r >= NT){
        const int rw = r - NT;
        const float* src = (rw >= 256) ? (W1r + (size_t)(rw - 256) * HD)
                                       : (W1q + (size_t)rw * HD);
        float4 a = *(const float4*)&src[tid * 8];
        float4 c = *(const float4*)&src[tid * 8 + 4];
        uint4 p = {pack2bf(a.x, a.y), pack2bf(a.z, a.w),
                   pack2bf(c.x, c.y), pack2bf(c.z, c.w)};
        *(uint4*)&Wbf[(size_t)rw * HD + tid * 8] = p;
        return;
    }
    const float* src = (r < NQ) ? (q + (size_t)r * HD) : (R + (size_t)(r - NQ) * HD);
    const float* g  = (r < NQ) ? gq : gr;
    const float* bb = (r < NQ) ? bq : br;
    float4 x0 = *(const float4*)&src[tid * 8];
    float4 x1 = *(const float4*)&src[tid * 8 + 4];
    float v[8] = {x0.x, x0.y, x0.z, x0.w, x1.x, x1.y, x1.z, x1.w};
    float s = 0.f, sq = 0.f;
#pragma unroll
    for (int i = 0; i < 8; ++i){ s += v[i]; sq += v[i] * v[i]; }
    __shared__ float red[256];
    __shared__ float mS, rS;
    red[tid] = s; __syncthreads();
    for (int off = 128; off > 0; off >>= 1){
        if (tid < off) red[tid] += red[tid + off];
        __syncthreads();
    }
    float sum = red[0]; __syncthreads();
    red[tid] = sq; __syncthreads();
    for (int off = 128; off > 0; off >>= 1){
        if (tid < off) red[tid] += red[tid + off];
        __syncthreads();
    }
    if (tid == 0){
        float mean = sum * (1.0f / HD);
        float var  = red[0] * (1.0f / HD) - mean * mean;
        mS = mean;
        rS = rsqrtf(fmaxf(var, 0.0f) + 1e-5f);
    }
    __syncthreads();
    float mean = mS, rstd = rS;
    float4 g0 = *(const float4*)&g[tid * 8];
    float4 g1 = *(const float4*)&g[tid * 8 + 4];
    float4 b0 = *(const float4*)&bb[tid * 8];
    float4 b1 = *(const float4*)&bb[tid * 8 + 4];
    float gg[8] = {g0.x, g0.y, g0.z, g0.w, g1.x, g1.y, g1.z, g1.w};
    float bv[8] = {b0.x, b0.y, b0.z, b0.w, b1.x, b1.y, b1.z, b1.w};
    float h[8];
#pragma unroll
    for (int i = 0; i < 8; ++i) h[i] = (v[i] - mean) * rstd * gg[i] + bv[i];
    uint4 p = {pack2bf(h[0], h[1]), pack2bf(h[2], h[3]),
               pack2bf(h[4], h[5]), pack2bf(h[6], h[7])};
    *(uint4*)&Xbf[(size_t)r * HD + tid * 8] = p;
}

// ---------------- K2: HP[ks] = Xbf @ Wbf^T (K-half ks), bf16 MFMA.
__global__ __launch_bounds__(256)
void k2_mfma(const unsigned short* __restrict__ Xbf,
             const unsigned short* __restrict__ Wbf,
             float* __restrict__ HP){
    const int tid  = threadIdx.x;
    const int wave = tid >> 6, lane = tid & 63;
    const int quad = lane >> 4, col = lane & 15;
    const int mblk = blockIdx.x;
    const int nblk = blockIdx.y;
    const int ks   = blockIdx.z;
    const int inp  = mblk >> 6;
    const int mbase = mblk * 64 + (wave & 1) * 32;
    const int nbase = nblk * 128 + (wave >> 1) * 64;

    const unsigned short* A0 = Xbf + (size_t)(mbase + col) * HD + ks * 1024 + quad * 8;
    const unsigned short* A1 = A0 + (size_t)16 * HD;
    const unsigned short* B0 = Wbf + (size_t)(inp * 256 + nbase + col) * HD + ks * 1024 + quad * 8;
    const unsigned short* B1 = B0 + (size_t)16 * HD;
    const unsigned short* B2 = B0 + (size_t)32 * HD;
    const unsigned short* B3 = B0 + (size_t)48 * HD;

    f32x4 acc[2][4];
#pragma unroll
    for (int mi = 0; mi < 2; ++mi)
#pragma unroll
        for (int ni = 0; ni < 4; ++ni) acc[mi][ni] = (f32x4){0.f, 0.f, 0.f, 0.f};

    for (int s = 0; s < 32; ++s){
        const int ko = s * 32;
        s16x8 a0 = *(const s16x8*)(A0 + ko);
        s16x8 a1 = *(const s16x8*)(A1 + ko);
        s16x8 b0 = *(const s16x8*)(B0 + ko);
        s16x8 b1 = *(const s16x8*)(B1 + ko);
        s16x8 b2 = *(const s16x8*)(B2 + ko);
        s16x8 b3 = *(const s16x8*)(B3 + ko);
        acc[0][0] = __builtin_amdgcn_mfma_f32_16x16x32_bf16(a0, b0, acc[0][0], 0, 0, 0);
        acc[0][1] = __builtin_amdgcn_mfma_f32_16x16x32_bf16(a0, b1, acc[0][1], 0, 0, 0);
        acc[0][2] = __builtin_amdgcn_mfma_f32_16x16x32_bf16(a0, b2, acc[0][2], 0, 0, 0);
        acc[0][3] = __builtin_amdgcn_mfma_f32_16x16x32_bf16(a0, b3, acc[0][3], 0, 0, 0);
        acc[1][0] = __builtin_amdgcn_mfma_f32_16x16x32_bf16(a1, b0, acc[1][0], 0, 0, 0);
        acc[1][1] = __builtin_amdgcn_mfma_f32_16x16x32_bf16(a1, b1, acc[1][1], 0, 0, 0);
        acc[1][2] = __builtin_amdgcn_mfma_f32_16x16x32_bf16(a1, b2, acc[1][2], 0, 0, 0);
        acc[1][3] = __builtin_amdgcn_mfma_f32_16x16x32_bf16(a1, b3, acc[1][3], 0, 0, 0);
    }
    float* dst = HP + (size_t)ks * NT * D2;
#pragma unroll
    for (int mi = 0; mi < 2; ++mi){
#pragma unroll
        for (int ni = 0; ni < 4; ++ni){
#pragma unroll
            for (int reg = 0; reg < 4; ++reg){
                int m = mbase + mi * 16 + quad * 4 + reg;
                int n = nbase + ni * 16 + col;
                dst[(size_t)m * D2 + n] = acc[mi][ni][reg];
            }
        }
    }
}

// ---------------- K3: combine HP + bias + GELU, GEMM2, l2norm -> Z (fp32), Zbf (bf16)
__global__ __launch_bounds__(256)
void k3_gemm2(const float* __restrict__ HP,
              const float* __restrict__ b1q, const float* __restrict__ b1r,
              const float* __restrict__ W2q, const float* __restrict__ b2q,
              const float* __restrict__ W2r, const float* __restrict__ b2r,
              float* __restrict__ Z, unsigned short* __restrict__ Zbf){
    const int gstart = blockIdx.x * 32;
    const int inp = (gstart >= NQ) ? 1 : 0;
    const float* b1 = inp ? b1r : b1q;
    const float* W2 = inp ? W2r : W2q;
    const float* b2 = inp ? b2r : b2q;

    __shared__ __align__(16) float Hs[32][68];
    __shared__ __align__(16) float Wk[64][132];
    __shared__ float red[32][17];
    __shared__ float normS[32];

    const int tid = threadIdx.x;
    const int ty = tid >> 4;
    const int tx = tid & 15;

    float acc[2][8];
#pragma unroll
    for (int jj = 0; jj < 8; ++jj){ acc[0][jj] = 0.f; acc[1][jj] = 0.f; }

    for (int kc = 0; kc < 4; ++kc){
#pragma unroll
        for (int i = 0; i < 8; ++i){
            int e = tid + i * 256;
            int rr = e >> 6, kk = e & 63;
            size_t idx = (size_t)(gstart + rr) * D2 + kc * 64 + kk;
            float hv = HP[idx] + HP[(size_t)NT * D2 + idx] + b1[kc * 64 + kk];
            Hs[rr][kk] = gelu_exact(hv);
        }
#pragma unroll
        for (int i = 0; i < 32; ++i){
            int e = tid + i * 256;
            int nn = e >> 6, kk = e & 63;
            Wk[kk][nn] = W2[(size_t)nn * D2 + kc * 64 + kk];
        }
        __syncthreads();
#pragma unroll
        for (int k4 = 0; k4 < 16; ++k4){
            float a0[4], a1[4];
            float4 t0 = *(const float4*)&Hs[ty * 2][k4 * 4];
            a0[0] = t0.x; a0[1] = t0.y; a0[2] = t0.z; a0[3] = t0.w;
            float4 t1 = *(const float4*)&Hs[ty * 2 + 1][k4 * 4];
            a1[0] = t1.x; a1[1] = t1.y; a1[2] = t1.z; a1[3] = t1.w;
#pragma unroll
            for (int kq = 0; kq < 4; ++kq){
                float4 w0 = *(const float4*)&Wk[k4 * 4 + kq][tx * 8];
                float4 w1 = *(const float4*)&Wk[k4 * 4 + kq][tx * 8 + 4];
                float wv[8] = {w0.x, w0.y, w0.z, w0.w, w1.x, w1.y, w1.z, w1.w};
#pragma unroll
                for (int jj = 0; jj < 8; ++jj){
                    acc[0][jj] += a0[kq] * wv[jj];
                    acc[1][jj] += a1[kq] * wv[jj];
                }
            }
        }
        __syncthreads();
    }
    float v0[8], v1[8];
    float sq0 = 0.f, sq1 = 0.f;
#pragma unroll
    for (int jj = 0; jj < 8; ++jj){
        int c = tx * 8 + jj;
        v0[jj] = acc[0][jj] + b2[c];
        v1[jj] = acc[1][jj] + b2[c];
        sq0 += v0[jj] * v0[jj];
        sq1 += v1[jj] * v1[jj];
    }
    red[ty * 2][tx]     = sq0;
    red[ty * 2 + 1][tx] = sq1;
    __syncthreads();
    if (tid < 32){
        float s = 0.f;
#pragma unroll
        for (int t = 0; t < 16; ++t) s += red[tid][t];
        normS[tid] = 1.0f / fmaxf(sqrtf(s), 1e-12f);
    }
    __syncthreads();
    float s0 = normS[ty * 2], s1 = normS[ty * 2 + 1];
    int row0 = gstart + ty * 2, row1 = row0 + 1;
    size_t o0 = (size_t)row0 * DD + tx * 8;
    size_t o1 = (size_t)row1 * DD + tx * 8;
    float z0[8], z1[8];
#pragma unroll
    for (int jj = 0; jj < 8; ++jj){ z0[jj] = v0[jj] * s0; z1[jj] = v1[jj] * s1; }
    float4 a = {z0[0], z0[1], z0[2], z0[3]}, b = {z0[4], z0[5], z0[6], z0[7]};
    float4 c = {z1[0], z1[1], z1[2], z1[3]}, d = {z1[4], z1[5], z1[6], z1[7]};
    *(float4*)&Z[o0]     = a;  *(float4*)&Z[o0 + 4] = b;
    *(float4*)&Z[o1]     = c;  *(float4*)&Z[o1 + 4] = d;
    uint4 p0 = {pack2bf(z0[0], z0[1]), pack2bf(z0[2], z0[3]),
                pack2bf(z0[4], z0[5]), pack2bf(z0[6], z0[7])};
    uint4 p1 = {pack2bf(z1[0], z1[1]), pack2bf(z1[2], z1[3]),
                pack2bf(z1[4], z1[5]), pack2bf(z1[6], z1[7])};
    *(uint4*)&Zbf[o0] = p0;
    *(uint4*)&Zbf[o1] = p1;
}

// ---------------- KT: ZbfT[d][r] = Zbf[NQ + r][d]  (r part only), tile 64x128.
__global__ __launch_bounds__(256)
void kT_transpose(const unsigned short* __restrict__ Zbf,
                  unsigned short* __restrict__ ZbfT){
    __shared__ unsigned short Ts[64][129];
    const int r0 = blockIdx.x * 64;
    const int tid = threadIdx.x;
#pragma unroll
    for (int i = 0; i < 32; ++i){
        int e = tid + i * 256;
        int rr = e >> 7, dd = e & 127;
        Ts[rr][dd] = Zbf[(size_t)(NQ + r0 + rr) * DD + dd];
    }
    __syncthreads();
#pragma unroll
    for (int i = 0; i < 32; ++i){
        int e = tid + i * 256;
        int dd = e >> 6, rr = e & 63;
        ZbfT[(size_t)dd * NQ + r0 + rr] = Ts[rr][dd];
    }
}

// ---------------- KA v9: flash attention, 32 q-rows/wave, V-prefetch.
// Block: 4 waves x 32 rows = 128 q-rows. Grid (32, NSPLIT).
// Per it (64 r-rows): prefetch 16 V-frags into regs (latency hides under
// QK+exp); 16 K-loads feed 32 QK MFMAs (2 m-subtiles); Pt per-wave in LDS;
// 16 prefetched V-frags feed 32 PV MFMAs.
__global__ __launch_bounds__(256, 2)
void kA_attn(const unsigned short* __restrict__ Zbf,
             const unsigned short* __restrict__ ZbfT,
             float* __restrict__ OP, float* __restrict__ LW){
    const int tid  = threadIdx.x;
    const int wave = tid >> 6, lane = tid & 63;
    const int quad = lane >> 4, col = lane & 15;
    const int m0   = blockIdx.x * 128 + wave * 32;
    const int split = blockIdx.y;
    const float scl = 0.08838834764831845f;   // 1/sqrt(128)

    __shared__ __align__(16) unsigned short Pt[4][2][16][72];  // per-wave, 2 m-subtiles

    s16x8 aq[2][4];
#pragma unroll
    for (int m = 0; m < 2; ++m)
#pragma unroll
        for (int kb = 0; kb < 4; ++kb)
            aq[m][kb] = *(const s16x8*)&Zbf[(size_t)(m0 + m * 16 + col) * DD + kb * 32 + quad * 8];

    f32x4 o[2][8];
#pragma unroll
    for (int m = 0; m < 2; ++m)
#pragma unroll
        for (int dt = 0; dt < 8; ++dt) o[m][dt] = (f32x4){0.f, 0.f, 0.f, 0.f};
    float lp[2][4] = {{0.f,0.f,0.f,0.f},{0.f,0.f,0.f,0.f}};
    float wp[2][4] = {{0.f,0.f,0.f,0.f},{0.f,0.f,0.f,0.f}};

    for (int it = 0; it < NIT; ++it){
        const int r0 = split * KPS + it * 64;

        // ---- V prefetch (16 frags, 64 VGPR) — issued before QK so the
        // global latency overlaps QK MFMAs + exp chain.
        s16x8 bv[8][2];
#pragma unroll
        for (int dt = 0; dt < 8; ++dt)
#pragma unroll
            for (int kb2 = 0; kb2 < 2; ++kb2)
                bv[dt][kb2] = *(const s16x8*)&ZbfT[(size_t)(dt * 16 + col) * NQ + r0 + kb2 * 32 + quad * 8];

        // ---- QK^T + exp for both m-subtiles.
#pragma unroll
        for (int nt = 0; nt < 4; ++nt){
            s16x8 b[4];
#pragma unroll
            for (int kb = 0; kb < 4; ++kb)
                b[kb] = *(const s16x8*)&Zbf[(size_t)(NQ + r0 + nt * 16 + col) * DD + kb * 32 + quad * 8];
#pragma unroll
            for (int m = 0; m < 2; ++m){
                f32x4 s = (f32x4){0.f, 0.f, 0.f, 0.f};
#pragma unroll
                for (int kb = 0; kb < 4; ++kb)
                    s = __builtin_amdgcn_mfma_f32_16x16x32_bf16(aq[m][kb], b[kb], s, 0, 0, 0);
#pragma unroll
                for (int reg = 0; reg < 4; ++reg){
                    float sv = s[reg] * scl;
                    float e  = __expf(sv);
                    lp[m][reg] += e;
                    wp[m][reg] += e * sv;
                    Pt[wave][m][quad * 4 + reg][nt * 16 + col] = f2bf(e);
                }
            }
        }

        // ---- PV using prefetched V.
#pragma unroll
        for (int m = 0; m < 2; ++m){
            s16x8 ap[2];
#pragma unroll
            for (int kb2 = 0; kb2 < 2; ++kb2)
                ap[kb2] = *(const s16x8*)&Pt[wave][m][col][kb2 * 32 + quad * 8];
#pragma unroll
            for (int dt = 0; dt < 8; ++dt)
#pragma unroll
                for (int kb2 = 0; kb2 < 2; ++kb2)
                    o[m][dt] = __builtin_amdgcn_mfma_f32_16x16x32_bf16(ap[kb2], bv[dt][kb2], o[m][dt], 0, 0, 0);
        }
    }

#pragma unroll
    for (int m = 0; m < 2; ++m)
#pragma unroll
    for (int reg = 0; reg < 4; ++reg){
        float l = lp[m][reg], w = wp[m][reg];
        l += __shfl_xor(l, 8);  w += __shfl_xor(w, 8);
        l += __shfl_xor(l, 4);  w += __shfl_xor(w, 4);
        l += __shfl_xor(l, 2);  w += __shfl_xor(w, 2);
        l += __shfl_xor(l, 1);  w += __shfl_xor(w, 1);
        if (col == 0){
            int row = m0 + m * 16 + quad * 4 + reg;
            LW[((size_t)split * NQ + row) * 2]     = l;
            LW[((size_t)split * NQ + row) * 2 + 1] = w;
        }
    }
#pragma unroll
    for (int m = 0; m < 2; ++m)
#pragma unroll
    for (int dt = 0; dt < 8; ++dt){
#pragma unroll
        for (int reg = 0; reg < 4; ++reg){
            int row = m0 + m * 16 + quad * 4 + reg;
            OP[((size_t)split * NQ + row) * DD + dt * 16 + col] = o[m][dt][reg];
        }
    }
}

// ---------------- KC: combine NSPLIT splits -> r_bar, cos, u_n.
__global__ __launch_bounds__(128)
void kC_combine(const float* __restrict__ OP, const float* __restrict__ LW,
                const float* __restrict__ Z,
                float* __restrict__ RB, float* __restrict__ COS,
                float* __restrict__ ILW){
    const int r = blockIdx.x;
    const int c = threadIdx.x;
    float v = 0.f;
#pragma unroll
    for (int s = 0; s < NSPLIT; ++s) v += OP[((size_t)s * NQ + r) * DD + c];
    __shared__ float red[128];
    red[c] = v * v; __syncthreads();
    for (int off = 64; off > 0; off >>= 1){
        if (c < off) red[c] += red[c + off];
        __syncthreads();
    }
    float scale = 1.0f / fmaxf(sqrtf(red[0]), 1e-12f);
    __syncthreads();
    float rb = v * scale;
    RB[(size_t)r * DD + c] = rb;
    float zq = Z[(size_t)r * DD + c];
    red[c] = zq * rb; __syncthreads();
    for (int off = 64; off > 0; off >>= 1){
        if (c < off) red[c] += red[c + off];
        __syncthreads();
    }
    if (c == 0){
        COS[r] = red[0];
        float l = 0.f, w = 0.f;
#pragma unroll
        for (int s = 0; s < NSPLIT; ++s){
            l += LW[((size_t)s * NQ + r) * 2];
            w += LW[((size_t)s * NQ + r) * 2 + 1];
        }
        float ent = logf(l) - w / l;
        ILW[2 * r]     = 1.0f / l;
        ILW[2 * r + 1] = ent * (1.0f / 8.317766166719343f);  // / ln(4096)
    }
}

// ---------------- K8: decoder MLP (occupancy rewrite, unchanged from v7).
__global__ __launch_bounds__(256)
void k8_decoder(const float* __restrict__ Z, const float* __restrict__ RB,
                const float* __restrict__ ILW, const float* __restrict__ COS,
                const float* __restrict__ gd, const float* __restrict__ bd,
                const float* __restrict__ W1d, const float* __restrict__ b1d,
                const float* __restrict__ W2d, const float* __restrict__ b2d,
                const float* __restrict__ beta, const float* __restrict__ W_len,
                const float* __restrict__ b_len,
                float* __restrict__ out){
    const int r0 = blockIdx.x * 4;
    const int tid = threadIdx.x;
    const int wave = tid >> 6, lane = tid & 63;

    __shared__ __align__(16) float Xs[4][256];
    __shared__ float pr[4][2];

    {
        const int row = r0 + wave;
        const int c0 = lane * 4;
        float4 v;
        if (c0 < DD) v = *(const float4*)&Z[(size_t)row * DD + c0];
        else         v = *(const float4*)&RB[(size_t)row * DD + (c0 - DD)];
        float s  = v.x + v.y + v.z + v.w;
        float sq = v.x * v.x + v.y * v.y + v.z * v.z + v.w * v.w;
#pragma unroll
        for (int off = 32; off > 0; off >>= 1){
            s  += __shfl_xor(s, off);
            sq += __shfl_xor(sq, off);
        }
        float mean = s * (1.0f / D2);
        float var  = sq * (1.0f / D2) - mean * mean;
        float rstd = rsqrtf(fmaxf(var, 0.0f) + 1e-5f);
        float4 g = *(const float4*)&gd[c0];
        float4 b = *(const float4*)&bd[c0];
        float4 xn;
        xn.x = (v.x - mean) * rstd * g.x + b.x;
        xn.y = (v.y - mean) * rstd * g.y + b.y;
        xn.z = (v.z - mean) * rstd * g.z + b.z;
        xn.w = (v.w - mean) * rstd * g.w + b.w;
        *(float4*)&Xs[wave][c0] = xn;
    }
    __syncthreads();

    const int j  = tid & 127;
    const int rp = tid >> 7;
    const float* wrow = W1d + (size_t)j * D2;
    const float* xa = &Xs[rp * 2][0];
    const float* xb = &Xs[rp * 2 + 1][0];
    float h0 = 0.f, h1 = 0.f;
#pragma unroll 8
    for (int k = 0; k < D2; k += 4){
        float4 w  = *(const float4*)&wrow[k];
        float4 a4 = *(const float4*)&xa[k];
        float4 b4 = *(const float4*)&xb[k];
        h0 += w.x * a4.x + w.y * a4.y + w.z * a4.z + w.w * a4.w;
        h1 += w.x * b4.x + w.y * b4.y + w.z * b4.z + w.w * b4.w;
    }
    float bj = b1d[j];
    h0 = gelu_exact(h0 + bj);
    h1 = gelu_exact(h1 + bj);
    float w2 = W2d[j];
    float p0 = h0 * w2, p1 = h1 * w2;
#pragma unroll
    for (int off = 32; off > 0; off >>= 1){
        p0 += __shfl_xor(p0, off);
        p1 += __shfl_xor(p1, off);
    }
    if (lane == 0){ pr[wave][0] = p0; pr[wave][1] = p1; }
    __syncthreads();

    if (tid < 4){
        const int row   = tid;
        const int rpair = row >> 1, rlo = row & 1;
        float lg = b2d[0] + pr[rpair * 2][rlo] + pr[rpair * 2 + 1][rlo];
        const int gr = r0 + row;
        float u  = ILW[2 * gr + 1];
        float cv = COS[gr];
        float dln = cv * W_len[0] + u * W_len[1] + b_len[0];
        float dt = beta[0] * u + beta[1] * tanhf(dln);
        dt = fminf(0.5f, fmaxf(-0.5f, dt));
        out[gr]      = lg;
        out[NQ + gr] = dt;
    }
}

extern "C" void kernel_launch(void* const* d_in, const int* in_sizes, int n_in,
                              void* d_out, int out_size, void* d_ws, size_t ws_size,
                              hipStream_t stream){
    const float* q      = (const float*)d_in[0];
    const float* R      = (const float*)d_in[1];
    const float* ln_q_g = (const float*)d_in[2];
    const float* ln_q_b = (const float*)d_in[3];
    const float* W1q    = (const float*)d_in[4];
    const float* b1q    = (const float*)d_in[5];
    const float* W2q    = (const float*)d_in[6];
    const float* b2q    = (const float*)d_in[7];
    const float* ln_r_g = (const float*)d_in[8];
    const float* ln_r_b = (const float*)d_in[9];
    const float* W1r    = (const float*)d_in[10];
    const float* b1r    = (const float*)d_in[11];
    const float* W2r    = (const float*)d_in[12];
    const float* b2r    = (const float*)d_in[13];
    const float* ln_d_g = (const float*)d_in[14];
    const float* ln_d_b = (const float*)d_in[15];
    const float* W1d    = (const float*)d_in[16];
    const float* b1d    = (const float*)d_in[17];
    const float* W2d    = (const float*)d_in[18];
    const float* b2d    = (const float*)d_in[19];
    const float* beta   = (const float*)d_in[20];
    const float* W_len  = (const float*)d_in[21];
    const float* b_len  = (const float*)d_in[22];

    float* WS = (float*)d_ws;
    unsigned short* Xbf  = (unsigned short*)(WS);             // 8192*2048 bf16 = 8388608 fl
    float* OP    = WS;                                        // [16][4096][128] aliases Xbf (dead after k2) — exact fit
    float* HP    = WS + 8388608;                              // 2*8192*256
    float* LW    = WS + 8388608;                              // [16][4096][2] aliases HP (dead after k3)
    unsigned short* Wbf  = (unsigned short*)(WS + 12582912);  // 512*2048 bf16
    float* Z     = WS + 13107200;                             // 8192*128
    unsigned short* Zbf  = (unsigned short*)(WS + 14155776);  // 8192*128 bf16
    unsigned short* ZbfT = (unsigned short*)(WS + 14680064);  // 128*4096 bf16
    float* RB    = WS + 14942208;                             // 4096*128
    float* COSV  = WS + 15466496;                             // 4096
    float* ILW   = WS + 15470592;                             // 4096*2
    float* out   = (float*)d_out;

    hipLaunchKernelGGL(kLN_cast, dim3(NT + 512), dim3(256), 0, stream,
                       q, R, ln_q_g, ln_q_b, ln_r_g, ln_r_b, W1q, W1r, Xbf, Wbf);
    hipLaunchKernelGGL(k2_mfma, dim3(128, 2, 2), dim3(256), 0, stream, Xbf, Wbf, HP);
    hipLaunchKernelGGL(k3_gemm2, dim3(256), dim3(256), 0, stream,
                       HP, b1q, b1r, W2q, b2q, W2r, b2r, Z, Zbf);
    hipLaunchKernelGGL(kT_transpose, dim3(64), dim3(256), 0, stream, Zbf, ZbfT);
    hipLaunchKernelGGL(kA_attn, dim3(32, NSPLIT), dim3(256), 0, stream, Zbf, ZbfT, OP, LW);
    hipLaunchKernelGGL(kC_combine, dim3(NQ), dim3(128), 0, stream, OP, LW, Z, RB, COSV, ILW);
    hipLaunchKernelGGL(k8_decoder, dim3(1024), dim3(256), 0, stream,
                       Z, RB, ILW, COSV, ln_d_g, ln_d_b, W1d, b1d, W2d, b2d,
                       beta, W_len, b_len, out);
}